// Round 8
// baseline (874.476 us; speedup 1.0000x reference)
//
#include <hip/hip_runtime.h>
#include <hip/hip_bf16.h>
#include <stdint.h>

typedef _Float16 f16x8 __attribute__((ext_vector_type(8)));
typedef _Float16 f16x4 __attribute__((ext_vector_type(4)));
typedef float    f32x4 __attribute__((ext_vector_type(4)));

// async 16-B global->LDS DMA: per-lane global src, dest = wave-uniform base + lane*16
#define GLDS16(gptr, lptr) \
  __builtin_amdgcn_global_load_lds((const __attribute__((address_space(1))) void*)(gptr), \
                                   (__attribute__((address_space(3))) void*)(lptr), 16, 0, 0)

// counted vmcnt wait (literal immediate), full memory clobber (rule #18)
#define WAITV(N) asm volatile("s_waitcnt vmcnt(" #N ")" ::: "memory")

// ---- tiled ("DMA-image") activation layout ----
// element (row, col) at: ((rb*4 + c)*8 + sub)*512 + r*8 + j   (halves)
// rb=row>>6, r=row&63, c=col>>6, sub=(col>>3)&7, j=col&7.
__device__ __forceinline__ int tile_off(int rb, int c, int sub) {
    return ((rb * 4 + c) * 8 + sub) * 512;
}

// WP layout: [c(8)][d0b(4)][g(4)][sub(8)][nl(64)][j(8)] halves.
// Block 2048 also packs BC and zeroes the global-barrier counter.
__global__ __launch_bounds__(256) void prepack_weights(
    const float* __restrict__ Wih, const float* __restrict__ Whh,
    const float* __restrict__ bih, const float* __restrict__ bhh,
    _Float16* __restrict__ WP, float* __restrict__ BC, int* __restrict__ CNT)
{
    if (blockIdx.x == 2048) {
        int i = threadIdx.x;
        BC[i]       = bih[i] + bhh[i];
        BC[256 + i] = bih[256 + i] + bhh[256 + i];
        BC[512 + i] = bih[512 + i];
        BC[768 + i] = bhh[512 + i];
        if (i == 0) *CNT = 0;          // re-zeroed every launch/replay
        return;
    }
    int idx = blockIdx.x * 256 + threadIdx.x;   // 524288 total
    int j   = idx & 7;
    int nl  = (idx >> 3) & 63;
    int sub = (idx >> 9) & 7;
    int g   = (idx >> 12) & 3;
    int d0b = (idx >> 14) & 3;
    int c   = idx >> 16;
    int k = c * 64 + sub * 8 + j;
    int d = d0b * 64 + nl;
    float v = 0.f;
    if (g == 0)      v = (k < 256) ? Wih[d * 256 + k]         : Whh[d * 256 + (k - 256)];
    else if (g == 1) v = (k < 256) ? Wih[(256 + d) * 256 + k] : Whh[(256 + d) * 256 + (k - 256)];
    else if (g == 2) v = (k < 256) ? Wih[(512 + d) * 256 + k] : 0.f;
    else             v = (k >= 256) ? Whh[(512 + d) * 256 + (k - 256)] : 0.f;
    WP[idx] = (_Float16)v;
}

// fp32 leaf -> fp16, split even/odd rows into TILED XE / XO buffers.
__global__ __launch_bounds__(256) void convert_split(
    const float* __restrict__ leaf, _Float16* __restrict__ XE, _Float16* __restrict__ XO)
{
    int g = blockIdx.x * 256 + threadIdx.x;     // 131072 rows * 32 units
    int u = g & 31;
    int row = g >> 5;
    const float* src = leaf + (size_t)row * 256 + u * 8;
    float4 a = *(const float4*)src;
    float4 b = *(const float4*)(src + 4);
    f16x8 p;
    p[0] = (_Float16)a.x; p[1] = (_Float16)a.y; p[2] = (_Float16)a.z; p[3] = (_Float16)a.w;
    p[4] = (_Float16)b.x; p[5] = (_Float16)b.y; p[6] = (_Float16)b.z; p[7] = (_Float16)b.w;
    int ro = row >> 1;
    _Float16* dst = (row & 1) ? XO : XE;
    *(f16x8*)(dst + tile_off(ro >> 6, u >> 3, u & 7) + (ro & 63) * 8) = p;
}

// Big-level GRU cell (round-4 proven, unchanged). MT=8 only.
template<int MT, bool SWIZ>
__global__ __launch_bounds__(256, 2) void gru_cell(
    const _Float16* __restrict__ Xsrc,
    const _Float16* __restrict__ Hsrc,
    const _Float16* __restrict__ WP,
    const float* __restrict__ BC,
    _Float16* __restrict__ Hout,
    _Float16* __restrict__ Ee, _Float16* __restrict__ Eo, _Float16* __restrict__ HP,
    int M)
{
    (void)M;
    constexpr int AROW = MT * 16 * 8;
    constexpr int ASZ  = 8 * AROW;
    __shared__ __align__(16) _Float16 Alds[2 * ASZ];

    const int tid  = threadIdx.x;
    int bm, d0b;
    if (SWIZ) {
        int xcd = blockIdx.x & 7, slot = blockIdx.x >> 3;
        d0b = slot & 3;
        bm  = (slot >> 2) * 8 + xcd;
    } else {
        bm = blockIdx.x >> 2; d0b = blockIdx.x & 3;
    }
    const int wave = tid >> 6, lane = tid & 63;
    const int quad = lane >> 4, lo = lane & 15;

    const bool has_h = (Hsrc != nullptr);
    const int nch = has_h ? 8 : 4;

    f32x4 acc[MT][4];
#pragma unroll
    for (int a = 0; a < MT; ++a)
#pragma unroll
        for (int b = 0; b < 4; ++b) acc[a][b] = (f32x4){0.f, 0.f, 0.f, 0.f};
    f16x4 hinvh[MT];

    auto loadB = [&](int c, f16x8 (&bb)[2][3]) {
        const size_t cb = (size_t)(c * 4 + d0b) * 4;
        const int col = (wave * 16 + lo) * 8;
#pragma unroll
        for (int ks = 0; ks < 2; ++ks) {
            const int subb = ks * 4 + quad;
#pragma unroll
            for (int slot = 0; slot < 3; ++slot) {
                int g = (slot == 2) ? ((c < 4) ? 2 : 3) : slot;
                bb[ks][slot] = *(const f16x8*)(WP + ((cb + g) * 8 + subb) * 512 + col);
            }
        }
    };

    auto issueA = [&](int c, int buf) {
        const _Float16* base = (c < 4) ? Xsrc : Hsrc;
        const int cc = c & 3;
        _Float16* Ab = Alds + buf * ASZ;
        constexpr int ND = MT / 2;
#pragma unroll
        for (int i = 0; i < ND; ++i) {
            int ai = wave * ND + i;
            int sub = ai >> 1, mh = ai & 1;
            GLDS16(base + tile_off(bm * (MT / 4) + mh, cc, sub) + lane * 8,
                   Ab + sub * AROW + mh * 512);
        }
    };

    auto compute = [&](int c, int buf, f16x8 (&bb)[2][3]) {
        const _Float16* Ab = Alds + buf * ASZ;
#pragma unroll
        for (int ks = 0; ks < 2; ++ks) {
            const int subb = ks * 4 + quad;
#pragma unroll
            for (int mt = 0; mt < MT; ++mt) {
                f16x8 a = *(const f16x8*)(Ab + subb * AROW + (mt * 16 + lo) * 8);
                acc[mt][0] = __builtin_amdgcn_mfma_f32_16x16x32_f16(a, bb[ks][0], acc[mt][0], 0, 0, 0);
                acc[mt][1] = __builtin_amdgcn_mfma_f32_16x16x32_f16(a, bb[ks][1], acc[mt][1], 0, 0, 0);
                if (c < 4)
                    acc[mt][2] = __builtin_amdgcn_mfma_f32_16x16x32_f16(a, bb[ks][2], acc[mt][2], 0, 0, 0);
                else
                    acc[mt][3] = __builtin_amdgcn_mfma_f32_16x16x32_f16(a, bb[ks][2], acc[mt][3], 0, 0, 0);
            }
        }
        if (has_h && c == 4 + d0b) {
            const int colw = wave * 16 + lo;
            const int sub = colw >> 3, j = colw & 7;
#pragma unroll
            for (int mt = 0; mt < MT; ++mt)
#pragma unroll
                for (int r = 0; r < 4; ++r)
                    hinvh[mt][r] = Ab[sub * AROW + (mt * 16 + quad * 4 + r) * 8 + j];
        }
    };

    issueA(0, 0);
    for (int c = 0; c < nch; ++c) {
        __syncthreads();
        f16x8 bb[2][3];
        loadB(c, bb);
        __builtin_amdgcn_sched_barrier(0);
        if (c + 1 < nch) issueA(c + 1, (c + 1) & 1);
        compute(c, c & 1, bb);
    }

    const int ld = wave * 16 + lo;
    const int d  = d0b * 64 + ld;
    const float brz0 = BC[d];
    const float brz1 = BC[256 + d];
    const float bni  = BC[512 + d];
    const float bnh  = BC[768 + d];
    constexpr int SROW = 72;
    constexpr int PR   = MT * 8;
    __syncthreads();
#pragma unroll
    for (int mt = 0; mt < MT; ++mt) {
        const int lr0 = mt * 16 + quad * 4;
        float hq[4];
#pragma unroll
        for (int r = 0; r < 4; ++r) {
            float hin = has_h ? (float)hinvh[mt][r] : 0.f;
            float rg = 1.f / (1.f + __expf(-(acc[mt][0][r] + brz0)));
            float zg = 1.f / (1.f + __expf(-(acc[mt][1][r] + brz1)));
            float ex = __expf(2.f * (acc[mt][2][r] + bni + rg * (acc[mt][3][r] + bnh)));
            float nv = 1.f - 2.f / (ex + 1.f);
            hq[r] = (1.f - zg) * nv + zg * hin;
            int lr = lr0 + r;
            if (Hout) {
                Alds[lr * SROW + ld] = (_Float16)hq[r];
            } else {
                Alds[(((lr & 1) * PR) + (lr >> 1)) * SROW + ld] =
                    (_Float16)(0.5f * (hin + hq[r]));
            }
        }
        if (!Hout) {
            Alds[(2 * PR + (lr0 >> 1)) * SROW + ld]     = (_Float16)(0.5f * (hq[0] + hq[1]));
            Alds[(2 * PR + (lr0 >> 1) + 1) * SROW + ld] = (_Float16)(0.5f * (hq[2] + hq[3]));
        }
    }
    __syncthreads();

    if (Hout) {
        constexpr int NU = MT * 128;
#pragma unroll
        for (int i = 0; i < NU / 256; ++i) {
            int uid = i * 256 + tid;
            int r = uid & 63, sub = (uid >> 6) & 7, mh = uid >> 9;
            f16x8 v = *(const f16x8*)&Alds[(mh * 64 + r) * SROW + sub * 8];
            *(f16x8*)(Hout + tile_off(bm * (MT / 4) + mh, d0b, sub) + r * 8) = v;
        }
    } else {
        constexpr int NU = 3 * PR * 8;
#pragma unroll
        for (int i = 0; i < NU / 256; ++i) {
            int uid = i * 256 + tid;
            int pr   = uid & (PR - 1);
            int rest = uid / PR;
            int sub = rest & 7, buf = rest >> 3;
            f16x8 v = *(const f16x8*)&Alds[(buf * PR + pr) * SROW + sub * 8];
            _Float16* dst = (buf == 0) ? Ee : (buf == 1) ? Eo : HP;
            *(f16x8*)(dst + tile_off(bm, d0b, sub) + pr * 8) = v;
        }
    }
}

// ---- MT=4 cell body (round-4 proven tail structure), as device function ----
// Triple-buffered A DMA, depth-2 prefetch, counted vmcnt; B direct to regs.
// Always has_h. Alds: 3 * 4096 halves (24 KB).
__device__ void cell4(const _Float16* __restrict__ Xsrc,
                      const _Float16* __restrict__ Hsrc,
                      const _Float16* __restrict__ WP,
                      const float* __restrict__ BC,
                      _Float16* Hout, _Float16* Ee, _Float16* Eo, _Float16* HP,
                      int bm, int d0b, int tid, _Float16* Alds)
{
    constexpr int MT   = 4;
    constexpr int AROW = 512;           // MT*16*8
    constexpr int ASZ  = 4096;          // 8*AROW
    const int wave = tid >> 6, lane = tid & 63;
    const int quad = lane >> 4, lo = lane & 15;

    f32x4 acc[MT][4];
#pragma unroll
    for (int a = 0; a < MT; ++a)
#pragma unroll
        for (int b = 0; b < 4; ++b) acc[a][b] = (f32x4){0.f, 0.f, 0.f, 0.f};
    f16x4 hinvh[MT];

    auto loadB = [&](int c, f16x8 (&bb)[2][3]) {
        const size_t cb = (size_t)(c * 4 + d0b) * 4;
        const int col = (wave * 16 + lo) * 8;
#pragma unroll
        for (int ks = 0; ks < 2; ++ks) {
            const int subb = ks * 4 + quad;
#pragma unroll
            for (int slot = 0; slot < 3; ++slot) {
                int g = (slot == 2) ? ((c < 4) ? 2 : 3) : slot;
                bb[ks][slot] = *(const f16x8*)(WP + ((cb + g) * 8 + subb) * 512 + col);
            }
        }
    };

    auto issueA = [&](int c, int buf) {     // 8 DMA issues, 2 per wave
        const _Float16* base = (c < 4) ? Xsrc : Hsrc;
        const int cc = c & 3;
        _Float16* Ab = Alds + buf * ASZ;
#pragma unroll
        for (int i = 0; i < 2; ++i) {
            int sub = wave * 2 + i;
            GLDS16(base + tile_off(bm, cc, sub) + lane * 8, Ab + sub * AROW);
        }
    };

    auto compute = [&](int c, int buf, f16x8 (&bb)[2][3]) {
        const _Float16* Ab = Alds + buf * ASZ;
#pragma unroll
        for (int ks = 0; ks < 2; ++ks) {
            const int subb = ks * 4 + quad;
#pragma unroll
            for (int mt = 0; mt < MT; ++mt) {
                f16x8 a = *(const f16x8*)(Ab + subb * AROW + (mt * 16 + lo) * 8);
                acc[mt][0] = __builtin_amdgcn_mfma_f32_16x16x32_f16(a, bb[ks][0], acc[mt][0], 0, 0, 0);
                acc[mt][1] = __builtin_amdgcn_mfma_f32_16x16x32_f16(a, bb[ks][1], acc[mt][1], 0, 0, 0);
                if (c < 4)
                    acc[mt][2] = __builtin_amdgcn_mfma_f32_16x16x32_f16(a, bb[ks][2], acc[mt][2], 0, 0, 0);
                else
                    acc[mt][3] = __builtin_amdgcn_mfma_f32_16x16x32_f16(a, bb[ks][2], acc[mt][3], 0, 0, 0);
            }
        }
        if (c == 4 + d0b) {
            const int colw = wave * 16 + lo;
            const int sub = colw >> 3, j = colw & 7;
#pragma unroll
            for (int mt = 0; mt < MT; ++mt)
#pragma unroll
                for (int r = 0; r < 4; ++r)
                    hinvh[mt][r] = Ab[sub * AROW + (mt * 16 + quad * 4 + r) * 8 + j];
        }
    };

    issueA(0, 0); issueA(1, 1);
    for (int c = 0; c < 8; ++c) {
        if (c < 7) WAITV(2); else WAITV(0);
        __builtin_amdgcn_s_barrier();
        __builtin_amdgcn_sched_barrier(0);
        f16x8 bb[2][3];
        loadB(c, bb);
        __builtin_amdgcn_sched_barrier(0);
        if (c + 2 < 8) issueA(c + 2, (c + 2) % 3);
        compute(c, c % 3, bb);
    }

    // ---- epilogue ----
    const int ld = wave * 16 + lo;
    const int d  = d0b * 64 + ld;
    const float brz0 = BC[d];
    const float brz1 = BC[256 + d];
    const float bni  = BC[512 + d];
    const float bnh  = BC[768 + d];
    constexpr int SROW = 72;
    constexpr int PR   = 32;            // MT*8
    __syncthreads();
#pragma unroll
    for (int mt = 0; mt < MT; ++mt) {
        const int lr0 = mt * 16 + quad * 4;
        float hq[4];
#pragma unroll
        for (int r = 0; r < 4; ++r) {
            float hin = (float)hinvh[mt][r];
            float rg = 1.f / (1.f + __expf(-(acc[mt][0][r] + brz0)));
            float zg = 1.f / (1.f + __expf(-(acc[mt][1][r] + brz1)));
            float ex = __expf(2.f * (acc[mt][2][r] + bni + rg * (acc[mt][3][r] + bnh)));
            float nv = 1.f - 2.f / (ex + 1.f);
            hq[r] = (1.f - zg) * nv + zg * hin;
            int lr = lr0 + r;
            if (Hout) {
                Alds[lr * SROW + ld] = (_Float16)hq[r];
            } else {
                Alds[(((lr & 1) * PR) + (lr >> 1)) * SROW + ld] =
                    (_Float16)(0.5f * (hin + hq[r]));
            }
        }
        if (!Hout) {
            Alds[(2 * PR + (lr0 >> 1)) * SROW + ld]     = (_Float16)(0.5f * (hq[0] + hq[1]));
            Alds[(2 * PR + (lr0 >> 1) + 1) * SROW + ld] = (_Float16)(0.5f * (hq[2] + hq[3]));
        }
    }
    __syncthreads();

    if (Hout) {
        constexpr int NU = 512;         // MT*128 16-B units
#pragma unroll
        for (int i = 0; i < NU / 256; ++i) {
            int uid = i * 256 + tid;
            int r = uid & 63, sub = (uid >> 6) & 7;
            f16x8 v = *(const f16x8*)&Alds[r * SROW + sub * 8];
            *(f16x8*)(Hout + tile_off(bm, d0b, sub) + r * 8) = v;
        }
    } else {
        constexpr int NU = 3 * PR * 8;  // 768 units
        const int rbE  = bm >> 1;
        const int roff = (bm & 1) * 32;
#pragma unroll
        for (int i = 0; i < NU / 256; ++i) {
            int uid = i * 256 + tid;
            int pr   = uid & (PR - 1);
            int rest = uid / PR;
            int sub = rest & 7, buf = rest >> 3;     // 0=Ee 1=Eo 2=HP
            f16x8 v = *(const f16x8*)&Alds[(buf * PR + pr) * SROW + sub * 8];
            _Float16* dst = (buf == 0) ? Ee : (buf == 1) ? Eo : HP;
            *(f16x8*)(dst + tile_off(rbE, d0b, sub) + (roff + pr) * 8) = v;
        }
    }
}

// ---- monotonic device-scope global barrier (256 blocks, all co-resident) ----
__device__ __forceinline__ void gbar(int* cnt, int target, int tid) {
    __syncthreads();                            // drains this block's stores (vmcnt)
    if (tid == 0) {
        __threadfence();                        // release: writeback to device scope
        atomicAdd(cnt, 1);
        while (__hip_atomic_load(cnt, __ATOMIC_RELAXED, __HIP_MEMORY_SCOPE_AGENT) < target)
            __builtin_amdgcn_s_sleep(2);
        __threadfence();                        // acquire: invalidate stale caches
    }
    __syncthreads();
}

// ---- persistent tail: levels 4..11 + final output, ONE ordinary launch ----
// grid = 256 blocks = #CUs, __launch_bounds__(256,1), 24 KB LDS -> all blocks
// resident at launch => software global barrier is safe.
__global__ __launch_bounds__(256, 1) void gru_tail_persist(
    _Float16* XAe, _Float16* XAo, _Float16* XBe, _Float16* XBo,
    const _Float16* __restrict__ WP, const float* __restrict__ BC,
    _Float16* H1, _Float16* HPa, _Float16* HPb2, int* cnt, float* out)
{
    __shared__ __align__(16) _Float16 Alds[3 * 4096];   // 24 KB
    const int tid = threadIdx.x;
    const int vb  = blockIdx.x;
    const int bm = vb >> 2, d0b = vb & 3;
    int bt = 0;

    for (int lev = 4; lev <= 11; ++lev) {
        const int M   = 65536 >> lev;
        const int nv  = ((M + 63) >> 6) * 4;    // active virtual blocks
        _Float16* Xe = (lev & 1) ? XBe : XAe;
        _Float16* Xo = (lev & 1) ? XBo : XAo;
        _Float16* De = (lev & 1) ? XAe : XBe;
        _Float16* Do = (lev & 1) ? XAo : XBo;
        _Float16* HPsrc = (lev & 1) ? HPb2 : HPa;
        _Float16* HPdst = (lev & 1) ? HPa : HPb2;
        if (vb < nv)
            cell4(Xe, HPsrc, WP, BC, H1, nullptr, nullptr, nullptr, bm, d0b, tid, Alds);
        bt += 256; gbar(cnt, bt, tid);
        if (vb < nv)
            cell4(Xo, H1, WP, BC, nullptr, De, Do, HPdst, bm, d0b, tid, Alds);
        bt += 256; gbar(cnt, bt, tid);
    }
    // final: lev 11 (odd) wrote De=XAe / Do=XAo; answer = 32 rows x 256 cols
    if (vb < 32) {
        int col = tid;
        const _Float16* src = (vb & 1) ? XAo : XAe;
        int r = vb >> 1;                        // 0..15, all in tile 0
        out[vb * 256 + col] =
            (float)src[tile_off(0, col >> 6, (col >> 3) & 7) + r * 8 + (col & 7)];
    }
}

extern "C" void kernel_launch(void* const* d_in, const int* in_sizes, int n_in,
                              void* d_out, int out_size, void* d_ws, size_t ws_size,
                              hipStream_t stream) {
    const float* leaf = (const float*)d_in[0];
    const float* Wih  = (const float*)d_in[1];
    const float* Whh  = (const float*)d_in[2];
    const float* bih  = (const float*)d_in[3];
    const float* bhh  = (const float*)d_in[4];

    char* ws = (char*)d_ws;
    _Float16* WPp = (_Float16*)ws;                         //  1 MB
    _Float16* XAe = (_Float16*)(ws + (1ull  << 20));       // 32 MB
    _Float16* XAo = (_Float16*)(ws + (33ull << 20));       // 32 MB
    _Float16* XBe = (_Float16*)(ws + (65ull << 20));       // 16 MB
    _Float16* XBo = (_Float16*)(ws + (81ull << 20));       // 16 MB
    _Float16* H1  = (_Float16*)(ws + (97ull << 20));       // 32 MB (big levels + tail H1)
    _Float16* HP2 = (_Float16*)(ws + (113ull << 20));      // tail HP ping (time-disjoint with big H1)
    _Float16* HPb = (_Float16*)(ws + (129ull << 20));      // 16 MB
    float*    BCp = (float*)(ws + (145ull << 20));         //  4 KB
    int*      CNT = (int*)(ws + (145ull << 20) + 8192);    //  barrier counter

    prepack_weights<<<2049, 256, 0, stream>>>(Wih, Whh, bih, bhh, WPp, BCp, CNT);
    convert_split<<<16384, 256, 0, stream>>>(leaf, XAe, XAo);

    // big levels 0..3 (proven round-4 structure)
    _Float16 *XeC = XAe, *XoC = XAo, *XeN = XBe, *XoN = XBo;
    const _Float16* hp = nullptr;
    int M = 65536;
    for (int lev = 0; lev < 4; ++lev) {
        int grid = (M / 128) * 4;
        gru_cell<8, true><<<grid, 256, 0, stream>>>(XeC, hp, WPp, BCp,
                                                    H1, nullptr, nullptr, nullptr, M);
        gru_cell<8, true><<<grid, 256, 0, stream>>>(XoC, H1, WPp, BCp,
                                                    nullptr, XeN, XoN, HPb, M);
        hp = HPb;
        _Float16* t;
        t = XeC; XeC = XeN; XeN = t;
        t = XoC; XoC = XoN; XoN = t;
        M >>= 1;
    }
    // after 4 swaps: lev-3 E output in XAe/XAo, HPb holds its pair-avg.

    gru_tail_persist<<<256, 256, 0, stream>>>(XAe, XAo, XBe, XBo, WPp, BCp,
                                              H1, HPb, HP2, CNT, (float*)d_out);
}